// Round 3
// baseline (50.536 us; speedup 1.0000x reference)
//
#include <hip/hip_runtime.h>
#include <hip/hip_bf16.h>

// okl = log_C_kappa + kappa + mean_j log( sum_i exp(kappa*<mu_n_i,z_j> - kappa) )
//       - log(M) - log_C_zero
// M = 2048 components, J = M*n = 65536 sample columns, d = 32.
//
// A is pre-scaled by kappa*log2(e)/||mu||, the -kappa*log2(e) shift is folded
// into the MFMA C-operand, so the epilogue per element is exp2 + add only.
// Final reduction fused into the main kernel via last-block-done ticket.

typedef __attribute__((ext_vector_type(8))) short bf16x8;
typedef __attribute__((ext_vector_type(4))) float f32x4;
typedef __attribute__((ext_vector_type(8))) unsigned short u16x8;

#define LOG2E 1.44269504088896340736f

#if __has_builtin(__builtin_amdgcn_exp2f)
#define EXP2(x) __builtin_amdgcn_exp2f(x)
#else
#define EXP2(x) exp2f(x)
#endif

static __device__ __forceinline__ unsigned short f2bf(float f) {
  unsigned int u = __float_as_uint(f);
  u += 0x7FFFu + ((u >> 16) & 1u);   // round-to-nearest-even
  return (unsigned short)(u >> 16);
}

// Kernel 1: Abf = bf16(kappa*log2e * mu / ||mu||), shape [M, 32]. One row/lane.
// Also zeroes the completion ticket for the fused final reduction.
__global__ __launch_bounds__(64) void vmf_prep(const float* __restrict__ mu,
                                               const float* __restrict__ kp,
                                               unsigned short* __restrict__ Abf,
                                               unsigned int* __restrict__ cnt,
                                               int M) {
  int row = blockIdx.x * 64 + threadIdx.x;
  if (row == 0) *cnt = 0u;
  if (row >= M) return;
  const float4* m4 = (const float4*)(mu + (size_t)row * 32);
  float4 v[8];
  float ss = 0.f;
#pragma unroll
  for (int i = 0; i < 8; ++i) {
    v[i] = m4[i];
    ss += v[i].x * v[i].x + v[i].y * v[i].y + v[i].z * v[i].z + v[i].w * v[i].w;
  }
  float sc = kp[0] * LOG2E / sqrtf(ss);
  u16x8 o[4];
#pragma unroll
  for (int i = 0; i < 8; ++i) {
    o[i >> 1][(i & 1) * 4 + 0] = f2bf(v[i].x * sc);
    o[i >> 1][(i & 1) * 4 + 1] = f2bf(v[i].y * sc);
    o[i >> 1][(i & 1) * 4 + 2] = f2bf(v[i].z * sc);
    o[i >> 1][(i & 1) * 4 + 3] = f2bf(v[i].w * sc);
  }
  u16x8* dst = (u16x8*)(Abf + (size_t)row * 32);
#pragma unroll
  for (int i = 0; i < 4; ++i) dst[i] = o[i];
}

// Kernel 2: block = 64 columns (4 MFMA N-tiles) x 8 waves; each wave covers
// M/8 rows. Per-column exp2-sums combined in LDS, log'd, block-reduced to one
// partial; last block reduces all partials and writes the scalar output.
__global__ __launch_bounds__(512, 6) void vmf_main(
    const unsigned short* __restrict__ Abf, const float* __restrict__ z,
    const float* __restrict__ kp, float* __restrict__ part,
    unsigned int* __restrict__ cnt, const float* __restrict__ lck,
    const float* __restrict__ lc0, float* __restrict__ out, int M, int J) {
  const int lane = threadIdx.x & 63;
  const int wave = threadIdx.x >> 6;   // 0..7
  const int r = lane & 15;             // row (A) / col (B) within tile
  const int q = lane >> 4;             // k-octet quadrant
  const float kap = kp[0];
  const float S = kap * LOG2E;
  const f32x4 cinit = {-S, -S, -S, -S};
  const int colbase = blockIdx.x * 64;

  // Loop-invariant B fragments (4 tiles), fp32 -> bf16 on the fly.
  bf16x8 b0, b1, b2, b3;
  {
    const float* zp;
    float4 fa, fb;
#define LOADB(bb, t)                                                       \
    zp = z + (size_t)(colbase + (t)*16 + r) * 32 + q * 8;                  \
    fa = *(const float4*)zp; fb = *(const float4*)(zp + 4);                \
    bb[0] = (short)f2bf(fa.x); bb[1] = (short)f2bf(fa.y);                  \
    bb[2] = (short)f2bf(fa.z); bb[3] = (short)f2bf(fa.w);                  \
    bb[4] = (short)f2bf(fb.x); bb[5] = (short)f2bf(fb.y);                  \
    bb[6] = (short)f2bf(fb.z); bb[7] = (short)f2bf(fb.w);
    LOADB(b0, 0) LOADB(b1, 1) LOADB(b2, 2) LOADB(b3, 3)
#undef LOADB
  }

  const int mchunk = M >> 3;           // rows per wave (256)
  const unsigned short* ap = Abf + (size_t)(wave * mchunk + r) * 32 + q * 8;
  float a0 = 0.f, a1 = 0.f, a2 = 0.f, a3 = 0.f;
#pragma unroll 2
  for (int m = 0; m < mchunk; m += 16) {
    bf16x8 av = *(const bf16x8*)(ap + (size_t)m * 32);
    f32x4 c0 = __builtin_amdgcn_mfma_f32_16x16x32_bf16(av, b0, cinit, 0, 0, 0);
    f32x4 c1 = __builtin_amdgcn_mfma_f32_16x16x32_bf16(av, b1, cinit, 0, 0, 0);
    f32x4 c2 = __builtin_amdgcn_mfma_f32_16x16x32_bf16(av, b2, cinit, 0, 0, 0);
    f32x4 c3 = __builtin_amdgcn_mfma_f32_16x16x32_bf16(av, b3, cinit, 0, 0, 0);
    a0 += (EXP2(c0[0]) + EXP2(c0[1])) + (EXP2(c0[2]) + EXP2(c0[3]));
    a1 += (EXP2(c1[0]) + EXP2(c1[1])) + (EXP2(c1[2]) + EXP2(c1[3]));
    a2 += (EXP2(c2[0]) + EXP2(c2[1])) + (EXP2(c2[2]) + EXP2(c2[3]));
    a3 += (EXP2(c3[0]) + EXP2(c3[1])) + (EXP2(c3[2]) + EXP2(c3[3]));
  }

  // Sum the 4 row-quadrants per column (lanes l, l^16, l^32, l^48 share col).
  a0 += __shfl_xor(a0, 16); a0 += __shfl_xor(a0, 32);
  a1 += __shfl_xor(a1, 16); a1 += __shfl_xor(a1, 32);
  a2 += __shfl_xor(a2, 16); a2 += __shfl_xor(a2, 32);
  a3 += __shfl_xor(a3, 16); a3 += __shfl_xor(a3, 32);

  // Lane l owns block-column (l>>4)*16 + (l&15): pick tile q's accumulator.
  float v = (q == 0) ? a0 : (q == 1) ? a1 : (q == 2) ? a2 : a3;
  __shared__ float red[512];
  __shared__ int islast;
  red[wave * 64 + lane] = v;
  __syncthreads();

  if (wave == 0) {
    float s = 0.f;
#pragma unroll
    for (int w = 0; w < 8; ++w) s += red[w * 64 + lane];
    s = fmaxf(s, 1e-38f);
    float t = __logf(s);               // t_j for this block-column
    t += __shfl_xor(t, 1);  t += __shfl_xor(t, 2);
    t += __shfl_xor(t, 4);  t += __shfl_xor(t, 8);
    t += __shfl_xor(t, 16); t += __shfl_xor(t, 32);
    if (lane == 0) {
      part[blockIdx.x] = t;
      __threadfence();
      unsigned int tk = atomicAdd(cnt, 1u);
      islast = (tk == gridDim.x - 1) ? 1 : 0;
    }
  }
  __syncthreads();

  if (islast) {                        // one block: reduce all partials
    __threadfence();
    const int nblk = gridDim.x;
    float s = 0.f;
    for (int i = threadIdx.x; i < nblk; i += 512) s += part[i];
    red[threadIdx.x] = s;
    __syncthreads();
    for (int off = 256; off > 0; off >>= 1) {
      if (threadIdx.x < off) red[threadIdx.x] += red[threadIdx.x + off];
      __syncthreads();
    }
    if (threadIdx.x == 0) {
      float tbar = red[0] / (float)J;
      out[0] = lck[0] + kap + tbar - logf((float)M) - lc0[0];
    }
  }
}

extern "C" void kernel_launch(void* const* d_in, const int* in_sizes, int n_in,
                              void* d_out, int out_size, void* d_ws, size_t ws_size,
                              hipStream_t stream) {
  const float* mu  = (const float*)d_in[0];
  const float* z   = (const float*)d_in[1];
  const float* kp  = (const float*)d_in[2];
  const float* lck = (const float*)d_in[3];
  const float* lc0 = (const float*)d_in[4];
  const int M = in_sizes[0] / 32;   // 2048
  const int J = in_sizes[1] / 32;   // 65536 (= M * n_samples)

  char* ws = (char*)d_ws;
  unsigned short* Abf = (unsigned short*)ws;                 // M*32*2 = 128 KB
  size_t abytes = ((size_t)M * 32 * 2 + 255) & ~(size_t)255;
  float* part = (float*)(ws + abytes);                       // nblk floats
  const int nblk = J / 64;                                   // 1024
  unsigned int* cnt = (unsigned int*)(ws + abytes + ((size_t)nblk * 4 + 255 & ~(size_t)255));

  vmf_prep<<<(M + 63) / 64, 64, 0, stream>>>(mu, kp, Abf, cnt, M);
  vmf_main<<<nblk, 512, 0, stream>>>(Abf, z, kp, part, cnt, lck, lc0,
                                     (float*)d_out, M, J);
}

// Round 4
// 34.595 us; speedup vs baseline: 1.4608x; 1.4608x over previous
//
#include <hip/hip_runtime.h>
#include <hip/hip_bf16.h>

// okl = log_C_kappa + kappa + mean_j log( sum_i exp(kappa*<mu_n_i,z_j> - kappa) )
//       - log(M) - log_C_zero
// M = 2048 components, J = M*n = 65536 sample columns, d = 32.
//
// A is pre-scaled by kappa*log2(e)/||mu||, the -kappa*log2(e) shift is folded
// into the MFMA C-operand, so the epilogue per element is exp2 + add only.
// Block = 128 columns (8 MFMA N-tiles held in registers), 8 waves split M.

typedef __attribute__((ext_vector_type(8))) short bf16x8;
typedef __attribute__((ext_vector_type(4))) float f32x4;
typedef __attribute__((ext_vector_type(8))) unsigned short u16x8;

#define LOG2E 1.44269504088896340736f

#if __has_builtin(__builtin_amdgcn_exp2f)
#define EXP2(x) __builtin_amdgcn_exp2f(x)
#else
#define EXP2(x) exp2f(x)
#endif

static __device__ __forceinline__ unsigned short f2bf(float f) {
  unsigned int u = __float_as_uint(f);
  u += 0x7FFFu + ((u >> 16) & 1u);   // round-to-nearest-even
  return (unsigned short)(u >> 16);
}

// Kernel 1: Abf = bf16(kappa*log2e * mu / ||mu||), shape [M, 32]. One row/lane.
__global__ __launch_bounds__(64) void vmf_prep(const float* __restrict__ mu,
                                               const float* __restrict__ kp,
                                               unsigned short* __restrict__ Abf,
                                               int M) {
  int row = blockIdx.x * 64 + threadIdx.x;
  if (row >= M) return;
  const float4* m4 = (const float4*)(mu + (size_t)row * 32);
  float4 v[8];
  float ss = 0.f;
#pragma unroll
  for (int i = 0; i < 8; ++i) {
    v[i] = m4[i];
    ss += v[i].x * v[i].x + v[i].y * v[i].y + v[i].z * v[i].z + v[i].w * v[i].w;
  }
  float sc = kp[0] * LOG2E / sqrtf(ss);
  u16x8 o[4];
#pragma unroll
  for (int i = 0; i < 8; ++i) {
    o[i >> 1][(i & 1) * 4 + 0] = f2bf(v[i].x * sc);
    o[i >> 1][(i & 1) * 4 + 1] = f2bf(v[i].y * sc);
    o[i >> 1][(i & 1) * 4 + 2] = f2bf(v[i].z * sc);
    o[i >> 1][(i & 1) * 4 + 3] = f2bf(v[i].w * sc);
  }
  u16x8* dst = (u16x8*)(Abf + (size_t)row * 32);
#pragma unroll
  for (int i = 0; i < 4; ++i) dst[i] = o[i];
}

// Kernel 2: block = 128 columns (8 N-tiles in registers) x 8 waves; each wave
// covers M/8 rows with an explicitly prefetched A stream. Per-column exp2-sums
// combined in LDS, log'd, block-reduced to one partial per block.
__global__ __launch_bounds__(512) void vmf_main(const unsigned short* __restrict__ Abf,
                                                const float* __restrict__ z,
                                                const float* __restrict__ kp,
                                                float* __restrict__ part,
                                                int M) {
  const int lane = threadIdx.x & 63;
  const int wave = threadIdx.x >> 6;   // 0..7
  const int r = lane & 15;             // row (A) / col (B) within tile
  const int q = lane >> 4;             // k-octet quadrant
  const float S = kp[0] * LOG2E;
  const f32x4 cinit = {-S, -S, -S, -S};
  const int colbase = blockIdx.x * 128;

  // Loop-invariant B fragments (8 tiles), fp32 -> bf16 on the fly.
  bf16x8 b[8];
#pragma unroll
  for (int t = 0; t < 8; ++t) {
    const float* zp = z + (size_t)(colbase + t * 16 + r) * 32 + q * 8;
    float4 fa = *(const float4*)zp;
    float4 fb = *(const float4*)(zp + 4);
    b[t][0] = (short)f2bf(fa.x); b[t][1] = (short)f2bf(fa.y);
    b[t][2] = (short)f2bf(fa.z); b[t][3] = (short)f2bf(fa.w);
    b[t][4] = (short)f2bf(fb.x); b[t][5] = (short)f2bf(fb.y);
    b[t][6] = (short)f2bf(fb.z); b[t][7] = (short)f2bf(fb.w);
  }

  const int mchunk = M >> 3;           // rows per wave (256, power of 2)
  const unsigned short* ap = Abf + (size_t)(wave * mchunk + r) * 32 + q * 8;
  bf16x8 av = *(const bf16x8*)ap;
  float acc[8] = {0.f, 0.f, 0.f, 0.f, 0.f, 0.f, 0.f, 0.f};
  for (int m = 0; m < mchunk; m += 16) {
    const int mn = (m + 16) & (mchunk - 1);          // wraparound: branchless
    bf16x8 nxt = *(const bf16x8*)(ap + (size_t)mn * 32);
#pragma unroll
    for (int t = 0; t < 8; ++t) {
      f32x4 c = __builtin_amdgcn_mfma_f32_16x16x32_bf16(av, b[t], cinit, 0, 0, 0);
      acc[t] += (EXP2(c[0]) + EXP2(c[1])) + (EXP2(c[2]) + EXP2(c[3]));
    }
    av = nxt;
  }

  // Sum the 4 row-quadrants per column (lanes l, l^16, l^32, l^48 share col).
#pragma unroll
  for (int t = 0; t < 8; ++t) {
    acc[t] += __shfl_xor(acc[t], 16);
    acc[t] += __shfl_xor(acc[t], 32);
  }
  // Lane l owns block-cols (l>>4)*16+(l&15) (tiles 0-3) and +64 (tiles 4-7).
  float vlo = (q == 0) ? acc[0] : (q == 1) ? acc[1] : (q == 2) ? acc[2] : acc[3];
  float vhi = (q == 0) ? acc[4] : (q == 1) ? acc[5] : (q == 2) ? acc[6] : acc[7];

  __shared__ float rlo[8][64];
  __shared__ float rhi[8][64];
  rlo[wave][lane] = vlo;
  rhi[wave][lane] = vhi;
  __syncthreads();

  if (wave == 0) {
    float slo = 0.f, shi = 0.f;
#pragma unroll
    for (int w = 0; w < 8; ++w) { slo += rlo[w][lane]; shi += rhi[w][lane]; }
    slo = fmaxf(slo, 1e-38f);
    shi = fmaxf(shi, 1e-38f);
    float t = __logf(slo) + __logf(shi);   // 2 columns' t_j for this lane
    t += __shfl_xor(t, 1);  t += __shfl_xor(t, 2);
    t += __shfl_xor(t, 4);  t += __shfl_xor(t, 8);
    t += __shfl_xor(t, 16); t += __shfl_xor(t, 32);
    if (lane == 0) part[blockIdx.x] = t;   // sum over this block's 128 columns
  }
}

// Kernel 3: reduce per-block partials, apply constants.
__global__ __launch_bounds__(256) void vmf_final(const float* __restrict__ part, int n,
                                                 const float* __restrict__ kp,
                                                 const float* __restrict__ lck,
                                                 const float* __restrict__ lc0,
                                                 float* __restrict__ out,
                                                 int M, int J) {
  __shared__ float red[256];
  float s = 0.f;
  for (int i = threadIdx.x; i < n; i += 256) s += part[i];
  red[threadIdx.x] = s;
  __syncthreads();
  for (int off = 128; off > 0; off >>= 1) {
    if (threadIdx.x < off) red[threadIdx.x] += red[threadIdx.x + off];
    __syncthreads();
  }
  if (threadIdx.x == 0) {
    float tbar = red[0] / (float)J;
    out[0] = lck[0] + kp[0] + tbar - logf((float)M) - lc0[0];
  }
}

extern "C" void kernel_launch(void* const* d_in, const int* in_sizes, int n_in,
                              void* d_out, int out_size, void* d_ws, size_t ws_size,
                              hipStream_t stream) {
  const float* mu  = (const float*)d_in[0];
  const float* z   = (const float*)d_in[1];
  const float* kp  = (const float*)d_in[2];
  const float* lck = (const float*)d_in[3];
  const float* lc0 = (const float*)d_in[4];
  const int M = in_sizes[0] / 32;   // 2048
  const int J = in_sizes[1] / 32;   // 65536 (= M * n_samples)

  char* ws = (char*)d_ws;
  unsigned short* Abf = (unsigned short*)ws;                 // M*32*2 = 128 KB
  size_t abytes = ((size_t)M * 32 * 2 + 255) & ~(size_t)255;
  float* part = (float*)(ws + abytes);                       // nblk floats

  vmf_prep<<<(M + 63) / 64, 64, 0, stream>>>(mu, kp, Abf, M);
  const int nblk = J / 128;  // 512 blocks, 8 waves each
  vmf_main<<<nblk, 512, 0, stream>>>(Abf, z, kp, part, M);
  vmf_final<<<1, 256, 0, stream>>>(part, nblk, kp, lck, lc0, (float*)d_out, M, J);
}